// Round 2
// baseline (693.317 us; speedup 1.0000x reference)
//
#include <hip/hip_runtime.h>
#include <hip/hip_bf16.h>

// B=2, N=512, C=256
// score[b,i,j] = sum_c relu(q_ic + k_jc) = 0.5*(Qs_i + Ks_j + sum_c |q_ic + k_jc|)
// Qs_i is constant per softmax row -> dropped. Kernel computes
// score'[i,j] = 0.5*(Sabs_ij + Ks_j); softmax weights identical to reference.

// ---------------- Kernel 1: fused QKV projection (unchanged, verified) ----------------
__global__ __launch_bounds__(256) void gemm_qkv(
    const float* __restrict__ x,
    const float* __restrict__ Wq, const float* __restrict__ Wk, const float* __restrict__ Wv,
    float* __restrict__ q, float* __restrict__ k, float* __restrict__ v)
{
    const int z = blockIdx.z;
    const float* W = (z == 0) ? Wq : ((z == 1) ? Wk : Wv);
    float* out = (z == 0) ? q : ((z == 1) ? k : v);
    const int row0 = blockIdx.x * 32;
    const int d0   = blockIdx.y * 64;

    __shared__ float AT[32][34];
    __shared__ float WT[32][68];

    const int tid = threadIdx.x;
    const int ty = tid >> 4, tx = tid & 15;

    float acc[2][4] = {};

    for (int c0 = 0; c0 < 256; c0 += 32) {
        {
            int r  = tid >> 3;
            int cg = (tid & 7) * 4;
            float4 a = *(const float4*)&x[(size_t)(row0 + r) * 256 + c0 + cg];
            AT[cg + 0][r] = a.x; AT[cg + 1][r] = a.y;
            AT[cg + 2][r] = a.z; AT[cg + 3][r] = a.w;
        }
        {
            int d  = tid >> 2;
            int cq = (tid & 3) * 8;
            float4 w0 = *(const float4*)&W[(size_t)(d0 + d) * 256 + c0 + cq];
            float4 w1 = *(const float4*)&W[(size_t)(d0 + d) * 256 + c0 + cq + 4];
            WT[cq + 0][d] = w0.x; WT[cq + 1][d] = w0.y;
            WT[cq + 2][d] = w0.z; WT[cq + 3][d] = w0.w;
            WT[cq + 4][d] = w1.x; WT[cq + 5][d] = w1.y;
            WT[cq + 6][d] = w1.z; WT[cq + 7][d] = w1.w;
        }
        __syncthreads();
#pragma unroll
        for (int c = 0; c < 32; ++c) {
            float2 a = *(const float2*)&AT[c][ty * 2];
            float4 w = *(const float4*)&WT[c][tx * 4];
            acc[0][0] += a.x * w.x; acc[0][1] += a.x * w.y;
            acc[0][2] += a.x * w.z; acc[0][3] += a.x * w.w;
            acc[1][0] += a.y * w.x; acc[1][1] += a.y * w.y;
            acc[1][2] += a.y * w.z; acc[1][3] += a.y * w.w;
        }
        __syncthreads();
    }
#pragma unroll
    for (int rr = 0; rr < 2; ++rr) {
        float4 o = make_float4(acc[rr][0], acc[rr][1], acc[rr][2], acc[rr][3]);
        *(float4*)&out[(size_t)(row0 + ty * 2 + rr) * 256 + d0 + tx * 4] = o;
    }
}

// ---------------- Kernel 2: attention partial ----------------
// Block: 512 thr (8 waves). Tile: 64 query rows (lane = row) x 32 keys (wave w owns j-quad 4w..4w+3).
// Grid (16 i-tiles, 16 j-splits). q staged per c-half in LDS (per-lane reads, stride 132 -> banks 4l+c,
// data-limited); k staged in LDS, read as wave-uniform broadcast b128. Score = 2 VALU/elem via abs-modifier.
// PV: v broadcast from LDS (reuses q buffer), p[32]/acc[32] fully in registers.
#define QSTR 132   // stride for 64x128 half-tiles: 132*4 B, 16B-aligned rows, banks (4*row+c)&31
#define VSTR 260   // stride for v 32x256: 16B-aligned rows

__global__ __launch_bounds__(512) void attn_partial(
    const float* __restrict__ q, const float* __restrict__ k, const float* __restrict__ v,
    float* __restrict__ pacc, float* __restrict__ ml)
{
    const int it = blockIdx.x;          // 0..15 : 64-row tile over flat rows (b*512+n)
    const int js = blockIdx.y;          // 0..15 : 32-key chunk within batch
    const int b  = it >> 3;
    const int irow0 = it * 64;
    const int jrow0 = b * 512 + js * 32;

    __shared__ float qbuf[64 * QSTR];   // 33792 B; reused as vS[32][VSTR] in PV
    __shared__ float kbuf[32 * QSTR];   // 16896 B
    __shared__ float sL[32][65];        //  8320 B
    __shared__ float KsS[32];

    const int t = threadIdx.x;
    const int w = t >> 6;               // wave 0..7
    const int l = t & 63;               // lane = local query row

    const int j0 = w * 4;               // wave's j-quad
    float s[4] = {0.f, 0.f, 0.f, 0.f};
    float kss = 0.f;
    const int ksj = t >> 4;             // 0..31
    const int ksc = (t & 15) * 8;

    for (int h = 0; h < 2; ++h) {
        // stage q half-tile 64x128 (coalesced global, data-limited LDS writes)
        {
            const float* qg = q + (size_t)irow0 * 256 + h * 128;
#pragma unroll
            for (int u = 0; u < 4; ++u) {
                int f = u * 2048 + t * 4;
                int r = f >> 7, c = f & 127;
                float4 a = *(const float4*)&qg[(size_t)r * 256 + c];
                *(float4*)&qbuf[r * QSTR + c] = a;
            }
        }
        // stage k half-tile 32x128
        {
            const float* kg = k + (size_t)jrow0 * 256 + h * 128;
#pragma unroll
            for (int u = 0; u < 2; ++u) {
                int f = u * 2048 + t * 4;
                int r = f >> 7, c = f & 127;
                float4 a = *(const float4*)&kg[(size_t)r * 256 + c];
                *(float4*)&kbuf[r * QSTR + c] = a;
            }
        }
        __syncthreads();

        // Ks partial: thread sums 8 c's of row ksj
        {
            float4 a = *(const float4*)&kbuf[ksj * QSTR + ksc];
            float4 bq = *(const float4*)&kbuf[ksj * QSTR + ksc + 4];
            kss += a.x + a.y + a.z + a.w + bq.x + bq.y + bq.z + bq.w;
        }

        // score: per 8-c chunk: q per-lane (2 x b128), k broadcast (2 x b128 per j)
        for (int c0 = 0; c0 < 128; c0 += 8) {
            float4 qa = *(const float4*)&qbuf[l * QSTR + c0];
            float4 qb = *(const float4*)&qbuf[l * QSTR + c0 + 4];
#pragma unroll
            for (int jj = 0; jj < 4; ++jj) {
                float4 ka = *(const float4*)&kbuf[(j0 + jj) * QSTR + c0];
                float4 kb = *(const float4*)&kbuf[(j0 + jj) * QSTR + c0 + 4];
                s[jj] += fabsf(qa.x + ka.x);
                s[jj] += fabsf(qa.y + ka.y);
                s[jj] += fabsf(qa.z + ka.z);
                s[jj] += fabsf(qa.w + ka.w);
                s[jj] += fabsf(qb.x + kb.x);
                s[jj] += fabsf(qb.y + kb.y);
                s[jj] += fabsf(qb.z + kb.z);
                s[jj] += fabsf(qb.w + kb.w);
            }
        }
        __syncthreads();   // protect restage of next half
    }

    // reduce Ks partials (16 threads per row) and publish
    {
        float kr = kss;
#pragma unroll
        for (int d = 1; d < 16; d <<= 1) kr += __shfl_xor(kr, d, 16);
        if ((t & 15) == 0) KsS[ksj] = kr;
    }
    __syncthreads();

    // publish scores: score' = 0.5*(Sabs + Ks_j)
#pragma unroll
    for (int jj = 0; jj < 4; ++jj)
        sL[j0 + jj][l] = 0.5f * (s[jj] + KsS[j0 + jj]);
    __syncthreads();

    // stage v (32x256) into qbuf (q no longer needed) + softmax (redundant per wave)
    {
        const float* vg = v + (size_t)jrow0 * 256;
#pragma unroll
        for (int u = 0; u < 4; ++u) {
            int f = u * 2048 + t * 4;
            int r = f >> 8, c = f & 255;
            float4 a = *(const float4*)&vg[f];
            *(float4*)&qbuf[r * VSTR + c] = a;
        }
    }
    float p[32];
#pragma unroll
    for (int j = 0; j < 32; ++j) p[j] = sL[j][l];
    float m = p[0];
#pragma unroll
    for (int j = 1; j < 32; ++j) m = fmaxf(m, p[j]);
    float lsum = 0.f;
#pragma unroll
    for (int j = 0; j < 32; ++j) { p[j] = __expf(p[j] - m); lsum += p[j]; }
    if (w == 0)
        *(float2*)&ml[((size_t)(irow0 + l) * 16 + js) * 2] = make_float2(m, lsum);
    __syncthreads();

    // PV: wave w -> c range [32w, 32w+32). v broadcast b128, acc[32] in regs.
    float acc[32];
#pragma unroll
    for (int i = 0; i < 32; ++i) acc[i] = 0.f;
    const int cbase = w * 32;
#pragma unroll
    for (int j = 0; j < 32; ++j) {
#pragma unroll
        for (int c4 = 0; c4 < 8; ++c4) {
            float4 vv = *(const float4*)&qbuf[j * VSTR + cbase + c4 * 4];
            acc[c4 * 4 + 0] += p[j] * vv.x;
            acc[c4 * 4 + 1] += p[j] * vv.y;
            acc[c4 * 4 + 2] += p[j] * vv.z;
            acc[c4 * 4 + 3] += p[j] * vv.w;
        }
    }
    // store pacc[it][js][c][lane]  (coalesced along lane)
    float* pb = pacc + (((size_t)it * 16 + js) * 256 + cbase) * 64 + l;
#pragma unroll
    for (int cc = 0; cc < 32; ++cc) pb[(size_t)cc * 64] = acc[cc];
}

// ---------------- Kernel 3: combine split-j partials -> O^T [256][1024] ----------------
__global__ __launch_bounds__(256) void combine(
    const float* __restrict__ pacc, const float* __restrict__ ml, float* __restrict__ OT)
{
    const int it = blockIdx.x;   // 0..15
    const int cs = blockIdx.y;   // 0..7 (32-c slice)
    const int t  = threadIdx.x;
    const int il = t & 63, cq = t >> 6;
    const int row = it * 64 + il;
    const int c0  = cs * 32 + cq * 8;

    float mv[16], lv[16], M = -1e30f;
#pragma unroll
    for (int s = 0; s < 16; ++s) {
        float2 e = *(const float2*)&ml[((size_t)row * 16 + s) * 2];
        mv[s] = e.x; lv[s] = e.y; M = fmaxf(M, e.x);
    }
    float L = 0.f;
    float o[8];
#pragma unroll
    for (int i = 0; i < 8; ++i) o[i] = 0.f;
#pragma unroll
    for (int s = 0; s < 16; ++s) {
        float wgt = __expf(mv[s] - M);
        L += wgt * lv[s];
        const float* pb = pacc + (((size_t)it * 16 + s) * 256 + c0) * 64 + il;
#pragma unroll
        for (int i = 0; i < 8; ++i) o[i] += wgt * pb[(size_t)i * 64];
    }
    float inv = 1.f / L;
#pragma unroll
    for (int i = 0; i < 8; ++i)
        OT[(size_t)(c0 + i) * 1024 + row] = o[i] * inv;
}

// ---------------- Kernel 4: final projection + bias (reads O^T) ----------------
__global__ __launch_bounds__(256) void gemm_bias(
    const float* __restrict__ OT, const float* __restrict__ W,
    const float* __restrict__ bias, float* __restrict__ out)
{
    const int row0 = blockIdx.x * 32;
    const int d0   = blockIdx.y * 64;

    __shared__ float AT[32][34];
    __shared__ float WT[32][68];

    const int tid = threadIdx.x;
    const int ty = tid >> 4, tx = tid & 15;

    float acc[2][4] = {};

    for (int c0 = 0; c0 < 256; c0 += 32) {
#pragma unroll
        for (int u = 0; u < 4; ++u) {
            int idx = u * 256 + tid;
            int cc = idx >> 5, r = idx & 31;
            AT[cc][r] = OT[(size_t)(c0 + cc) * 1024 + row0 + r];
        }
        {
            int d  = tid >> 2;
            int cq = (tid & 3) * 8;
            float4 w0 = *(const float4*)&W[(size_t)(d0 + d) * 256 + c0 + cq];
            float4 w1 = *(const float4*)&W[(size_t)(d0 + d) * 256 + c0 + cq + 4];
            WT[cq + 0][d] = w0.x; WT[cq + 1][d] = w0.y;
            WT[cq + 2][d] = w0.z; WT[cq + 3][d] = w0.w;
            WT[cq + 4][d] = w1.x; WT[cq + 5][d] = w1.y;
            WT[cq + 6][d] = w1.z; WT[cq + 7][d] = w1.w;
        }
        __syncthreads();
#pragma unroll
        for (int c = 0; c < 32; ++c) {
            float2 a = *(const float2*)&AT[c][ty * 2];
            float4 w = *(const float4*)&WT[c][tx * 4];
            acc[0][0] += a.x * w.x; acc[0][1] += a.x * w.y;
            acc[0][2] += a.x * w.z; acc[0][3] += a.x * w.w;
            acc[1][0] += a.y * w.x; acc[1][1] += a.y * w.y;
            acc[1][2] += a.y * w.z; acc[1][3] += a.y * w.w;
        }
        __syncthreads();
    }
    float4 bb = *(const float4*)&bias[d0 + tx * 4];
#pragma unroll
    for (int rr = 0; rr < 2; ++rr) {
        float4 o = make_float4(acc[rr][0] + bb.x, acc[rr][1] + bb.y,
                               acc[rr][2] + bb.z, acc[rr][3] + bb.w);
        *(float4*)&out[(size_t)(row0 + ty * 2 + rr) * 256 + d0 + tx * 4] = o;
    }
}

extern "C" void kernel_launch(void* const* d_in, const int* in_sizes, int n_in,
                              void* d_out, int out_size, void* d_ws, size_t ws_size,
                              hipStream_t stream) {
    const float* x  = (const float*)d_in[0];
    const float* Wq = (const float*)d_in[1];
    const float* Wk = (const float*)d_in[2];
    const float* Wv = (const float*)d_in[3];
    const float* Wp = (const float*)d_in[4];
    const float* bp = (const float*)d_in[5];
    float* out = (float*)d_out;
    (void)ws_size;

    float* ws = (float*)d_ws;
    const size_t BNC = (size_t)2 * 512 * 256;              // 262144
    float* q    = ws;
    float* k    = q + BNC;
    float* v    = k + BNC;
    float* OT   = v + BNC;                                 // [256][1024]
    float* pacc = OT + BNC;                                // [16][16][256][64] = 16 MB
    float* mlb  = pacc + (size_t)16 * 16 * 256 * 64;       // [1024][16][2]

    gemm_qkv<<<dim3(32, 4, 3), 256, 0, stream>>>(x, Wq, Wk, Wv, q, k, v);
    attn_partial<<<dim3(16, 16), 512, 0, stream>>>(q, k, v, pacc, mlb);
    combine<<<dim3(16, 8), 256, 0, stream>>>(pacc, mlb, OT);
    gemm_bias<<<dim3(32, 4), 256, 0, stream>>>(OT, Wp, bp, out);
}

// Round 3
// 67.962 us; speedup vs baseline: 10.2015x; 10.2015x over previous
//
#include <hip/hip_runtime.h>
#include <hip/hip_bf16.h>

// B=2, N=512, C=256
// score[b,i,j] = sum_c relu(q_ic + k_jc) = 0.5*(Qs_i + Ks_j + sum_c |q_ic + k_jc|)
// Qs_i is row-constant -> cancels in softmax. Kernel uses score' = 0.5*(Sabs_ij + Ks_j).

#define RFL(x) __builtin_amdgcn_readfirstlane(x)
#define QSTR 132   // q LDS stride (dwords): full-BW bank pattern for per-lane b128

// ---------------- Kernel 1: fused QKV projection ----------------
// tile 32 rows x 64 d, 256 thr, reg 2x4, K-chunk 32.
// z==0 -> q stored TRANSPOSED as qt4[c4][1024rows] (float4 of 4 consecutive c)
// z==1 -> k row-major + Ksp[dtile][row] partial row-sums (for the Ks_j term)
// z==2 -> v row-major
__global__ __launch_bounds__(256, 2) void gemm_qkv(
    const float* __restrict__ x,
    const float* __restrict__ Wq, const float* __restrict__ Wk, const float* __restrict__ Wv,
    float4* __restrict__ qt4, float* __restrict__ k, float* __restrict__ v,
    float* __restrict__ Ksp)
{
    const int z = blockIdx.z;
    const float* W = (z == 0) ? Wq : ((z == 1) ? Wk : Wv);
    const int row0 = blockIdx.x * 32;
    const int d0   = blockIdx.y * 64;

    __shared__ __attribute__((aligned(16))) float AT[32][36];  // [c][row]
    __shared__ __attribute__((aligned(16))) float WT[32][68];  // [c][d]

    const int tid = threadIdx.x;
    const int ty = tid >> 4, tx = tid & 15;

    float acc[2][4] = {};

    for (int c0 = 0; c0 < 256; c0 += 32) {
        {   // stage A 32x32 transposed
            int r  = tid >> 3;
            int cb = (tid & 7) * 4;
            float4 a = *(const float4*)&x[(size_t)(row0 + r) * 256 + c0 + cb];
            AT[cb + 0][r] = a.x; AT[cb + 1][r] = a.y;
            AT[cb + 2][r] = a.z; AT[cb + 3][r] = a.w;
        }
        {   // stage W 64x32 transposed
            int d  = tid >> 2;
            int cq = (tid & 3) * 8;
            float4 w0 = *(const float4*)&W[(size_t)(d0 + d) * 256 + c0 + cq];
            float4 w1 = *(const float4*)&W[(size_t)(d0 + d) * 256 + c0 + cq + 4];
            WT[cq + 0][d] = w0.x; WT[cq + 1][d] = w0.y;
            WT[cq + 2][d] = w0.z; WT[cq + 3][d] = w0.w;
            WT[cq + 4][d] = w1.x; WT[cq + 5][d] = w1.y;
            WT[cq + 6][d] = w1.z; WT[cq + 7][d] = w1.w;
        }
        __syncthreads();
#pragma unroll
        for (int c = 0; c < 32; ++c) {
            float2 a  = *(const float2*)&AT[c][ty * 2];
            float4 w4 = *(const float4*)&WT[c][tx * 4];
            acc[0][0] += a.x * w4.x; acc[0][1] += a.x * w4.y;
            acc[0][2] += a.x * w4.z; acc[0][3] += a.x * w4.w;
            acc[1][0] += a.y * w4.x; acc[1][1] += a.y * w4.y;
            acc[1][2] += a.y * w4.z; acc[1][3] += a.y * w4.w;
        }
        __syncthreads();
    }

    if (z == 0) {
        // q transposed store: qt4[(d0/4+tx)][row]
#pragma unroll
        for (int rr = 0; rr < 2; ++rr)
            qt4[(size_t)(d0 / 4 + tx) * 1024 + row0 + ty * 2 + rr] =
                make_float4(acc[rr][0], acc[rr][1], acc[rr][2], acc[rr][3]);
    } else {
        float* out = (z == 1) ? k : v;
#pragma unroll
        for (int rr = 0; rr < 2; ++rr)
            *(float4*)&out[(size_t)(row0 + ty * 2 + rr) * 256 + d0 + tx * 4] =
                make_float4(acc[rr][0], acc[rr][1], acc[rr][2], acc[rr][3]);
        if (z == 1) {
            // partial row-sums over this block's 64 d's
#pragma unroll
            for (int rr = 0; rr < 2; ++rr) {
                float kp = acc[rr][0] + acc[rr][1] + acc[rr][2] + acc[rr][3];
#pragma unroll
                for (int d = 1; d < 16; d <<= 1) kp += __shfl_xor(kp, d, 16);
                if (tx == 0)
                    Ksp[(size_t)(d0 >> 6) * 1024 + row0 + ty * 2 + rr] = kp;
            }
        }
    }
}

// ---------------- Kernel 2: attention partial (split-j) ----------------
// 512 thr = 8 waves. lane = query row (64 rows), wave w = j-quad {4w..4w+3}.
// q via LDS (per-lane b128, padded stride); k,v via SCALAR loads (readfirstlane-
// hoisted uniform addresses -> s_load, SGPR operand in VALU). Score: 2 VALU/elem.
__global__ __launch_bounds__(512, 2) void attn_partial(
    const float4* __restrict__ qt4, const float* __restrict__ kk,
    const float* __restrict__ vv, const float* __restrict__ Ksp,
    float* __restrict__ pacc, float* __restrict__ ml)
{
    const int it = blockIdx.x;          // 0..15 : 64-row tile (flat rows b*512+n)
    const int js = blockIdx.y;          // 0..15 : 32-key chunk within batch
    const int b  = it >> 3;
    const int irow0 = it * 64;
    const int jrow0 = b * 512 + js * 32;

    __shared__ __attribute__((aligned(16))) float qbuf[64 * QSTR];  // 33.8 KB
    __shared__ float sL[32][65];
    __shared__ float pl[32][65];

    const int t = threadIdx.x;
    const int w = t >> 6;               // wave 0..7
    const int l = t & 63;               // lane = local query row

    const int jbase = RFL(jrow0 + w * 4);       // wave's first global key row
    const float* kw = kk + (size_t)jbase * 256; // uniform -> scalar loads

    float s[4] = {0.f, 0.f, 0.f, 0.f};

    for (int h = 0; h < 2; ++h) {
        // stage q half-tile 64 rows x 128 c from qt4[c4][row] (coalesced)
#pragma unroll
        for (int u = 0; u < 4; ++u) {
            int idx = u * 512 + t;
            int c4 = idx >> 6, row = idx & 63;
            float4 a = qt4[(size_t)(h * 32 + c4) * 1024 + irow0 + row];
            *(float4*)&qbuf[row * QSTR + c4 * 4] = a;
        }
        __syncthreads();
        const float* kh = kw + h * 128;
        for (int c0 = 0; c0 < 128; c0 += 8) {
            float4 qa = *(const float4*)&qbuf[l * QSTR + c0];
            float4 qb = *(const float4*)&qbuf[l * QSTR + c0 + 4];
#pragma unroll
            for (int jj = 0; jj < 4; ++jj) {
                const float* kr = kh + jj * 256 + c0;   // uniform -> s_load
                s[jj] += fabsf(qa.x + kr[0]);
                s[jj] += fabsf(qa.y + kr[1]);
                s[jj] += fabsf(qa.z + kr[2]);
                s[jj] += fabsf(qa.w + kr[3]);
                s[jj] += fabsf(qb.x + kr[4]);
                s[jj] += fabsf(qb.y + kr[5]);
                s[jj] += fabsf(qb.z + kr[6]);
                s[jj] += fabsf(qb.w + kr[7]);
            }
        }
        __syncthreads();   // before restaging qbuf
    }

    // score' = 0.5*(Sabs + Ks_j); publish to LDS for cross-wave softmax
    float sc[4];
#pragma unroll
    for (int jj = 0; jj < 4; ++jj) {
        float ks = Ksp[jbase + jj] + Ksp[1024 + jbase + jj]
                 + Ksp[2048 + jbase + jj] + Ksp[3072 + jbase + jj];
        sc[jj] = 0.5f * (s[jj] + ks);
        sL[w * 4 + jj][l] = sc[jj];
    }
    __syncthreads();

    float m = -1e30f;
#pragma unroll
    for (int j = 0; j < 32; ++j) m = fmaxf(m, sL[j][l]);
#pragma unroll
    for (int jj = 0; jj < 4; ++jj)
        pl[w * 4 + jj][l] = __expf(sc[jj] - m);
    __syncthreads();

    if (w == 0) {
        float lsum = 0.f;
#pragma unroll
        for (int j = 0; j < 32; ++j) lsum += pl[j][l];
        *(float2*)&ml[((size_t)(irow0 + l) * 16 + js) * 2] = make_float2(m, lsum);
    }

    // PV: wave w owns c-range [32w,32w+32); v via scalar loads, p via 1 b32/j
    const int cb = w * 32;
    const float* vw = vv + (size_t)RFL(jrow0 * 256 + w * 32);  // uniform
    float acc[32];
#pragma unroll
    for (int i = 0; i < 32; ++i) acc[i] = 0.f;
#pragma unroll 2
    for (int j = 0; j < 32; ++j) {
        float pj = pl[j][l];
#pragma unroll
        for (int cc = 0; cc < 32; ++cc)
            acc[cc] += pj * vw[j * 256 + cc];   // v_fmac with SGPR src
    }
    float* pb = pacc + (((size_t)it * 16 + js) * 256 + cb) * 64 + l;
#pragma unroll
    for (int cc = 0; cc < 32; ++cc) pb[(size_t)cc * 64] = acc[cc];
}

// ---------------- Kernel 3: combine split-j partials -> O^T [256][1024] ----------------
__global__ __launch_bounds__(256) void combine(
    const float* __restrict__ pacc, const float* __restrict__ ml, float* __restrict__ OT)
{
    const int it = blockIdx.x;   // 0..15
    const int cs = blockIdx.y;   // 0..7 (32-c slice)
    const int t  = threadIdx.x;
    const int il = t & 63, cq = t >> 6;
    const int row = it * 64 + il;
    const int c0  = cs * 32 + cq * 8;

    float mv[16], lv[16], M = -1e30f;
#pragma unroll
    for (int s = 0; s < 16; ++s) {
        float2 e = *(const float2*)&ml[((size_t)row * 16 + s) * 2];
        mv[s] = e.x; lv[s] = e.y; M = fmaxf(M, e.x);
    }
    float L = 0.f;
    float o[8];
#pragma unroll
    for (int i = 0; i < 8; ++i) o[i] = 0.f;
#pragma unroll
    for (int s = 0; s < 16; ++s) {
        float wgt = __expf(mv[s] - M);
        L += wgt * lv[s];
        const float* pb = pacc + (((size_t)it * 16 + s) * 256 + c0) * 64 + il;
#pragma unroll
        for (int i = 0; i < 8; ++i) o[i] += wgt * pb[(size_t)i * 64];
    }
    float inv = 1.f / L;
#pragma unroll
    for (int i = 0; i < 8; ++i)
        OT[(size_t)(c0 + i) * 1024 + row] = o[i] * inv;
}

// ---------------- Kernel 4: final projection + bias (reads O^T) ----------------
__global__ __launch_bounds__(256, 2) void gemm_bias(
    const float* __restrict__ OT, const float* __restrict__ W,
    const float* __restrict__ bias, float* __restrict__ out)
{
    const int row0 = blockIdx.x * 32;
    const int d0   = blockIdx.y * 64;

    __shared__ __attribute__((aligned(16))) float AT[32][36];
    __shared__ __attribute__((aligned(16))) float WT[32][68];

    const int tid = threadIdx.x;
    const int ty = tid >> 4, tx = tid & 15;

    float acc[2][4] = {};

    for (int c0 = 0; c0 < 256; c0 += 32) {
        {   // stage A from OT[c][row]: no transpose needed
            int cc = tid >> 3, r = (tid & 7) * 4;
            float4 a = *(const float4*)&OT[(size_t)(c0 + cc) * 1024 + row0 + r];
            *(float4*)&AT[cc][r] = a;
        }
        {
            int d  = tid >> 2;
            int cq = (tid & 3) * 8;
            float4 w0 = *(const float4*)&W[(size_t)(d0 + d) * 256 + c0 + cq];
            float4 w1 = *(const float4*)&W[(size_t)(d0 + d) * 256 + c0 + cq + 4];
            WT[cq + 0][d] = w0.x; WT[cq + 1][d] = w0.y;
            WT[cq + 2][d] = w0.z; WT[cq + 3][d] = w0.w;
            WT[cq + 4][d] = w1.x; WT[cq + 5][d] = w1.y;
            WT[cq + 6][d] = w1.z; WT[cq + 7][d] = w1.w;
        }
        __syncthreads();
#pragma unroll
        for (int c = 0; c < 32; ++c) {
            float2 a  = *(const float2*)&AT[c][ty * 2];
            float4 w4 = *(const float4*)&WT[c][tx * 4];
            acc[0][0] += a.x * w4.x; acc[0][1] += a.x * w4.y;
            acc[0][2] += a.x * w4.z; acc[0][3] += a.x * w4.w;
            acc[1][0] += a.y * w4.x; acc[1][1] += a.y * w4.y;
            acc[1][2] += a.y * w4.z; acc[1][3] += a.y * w4.w;
        }
        __syncthreads();
    }
    float4 bb = *(const float4*)&bias[d0 + tx * 4];
#pragma unroll
    for (int rr = 0; rr < 2; ++rr) {
        float4 o = make_float4(acc[rr][0] + bb.x, acc[rr][1] + bb.y,
                               acc[rr][2] + bb.z, acc[rr][3] + bb.w);
        *(float4*)&out[(size_t)(row0 + ty * 2 + rr) * 256 + d0 + tx * 4] = o;
    }
}

extern "C" void kernel_launch(void* const* d_in, const int* in_sizes, int n_in,
                              void* d_out, int out_size, void* d_ws, size_t ws_size,
                              hipStream_t stream) {
    const float* x  = (const float*)d_in[0];
    const float* Wq = (const float*)d_in[1];
    const float* Wk = (const float*)d_in[2];
    const float* Wv = (const float*)d_in[3];
    const float* Wp = (const float*)d_in[4];
    const float* bp = (const float*)d_in[5];
    float* out = (float*)d_out;
    (void)ws_size; (void)in_sizes; (void)n_in; (void)out_size;

    float* ws = (float*)d_ws;
    const size_t BNC = (size_t)2 * 512 * 256;              // 262144
    float4* qt4 = (float4*)ws;                             // [64 c4][1024] = 1 MB
    float* k    = ws + BNC;
    float* v    = k + BNC;
    float* OT   = v + BNC;                                 // [256][1024]
    float* Ksp  = OT + BNC;                                // [4][1024]
    float* pacc = Ksp + 4 * 1024;                          // [16][16][256][64] = 16 MB
    float* mlb  = pacc + (size_t)16 * 16 * 256 * 64;       // [1024][16][2]

    gemm_qkv<<<dim3(32, 4, 3), 256, 0, stream>>>(x, Wq, Wk, Wv, qt4, k, v, Ksp);
    attn_partial<<<dim3(16, 16), 512, 0, stream>>>(qt4, k, v, Ksp, pacc, mlb);
    combine<<<dim3(16, 8), 256, 0, stream>>>(pacc, mlb, OT);
    gemm_bias<<<dim3(32, 4), 256, 0, stream>>>(OT, Wp, bp, out);
}